// Round 3
// baseline (271.319 us; speedup 1.0000x reference)
//
#include <hip/hip_runtime.h>
#include <math.h>

// Problem constants (from reference): B,V,C,D,H,W = 2,2,32,48,128,160
#define BB 2
#define VV 2
#define CC 32
#define DD 48
#define HH 128
#define WW 160
#define HWPIX (HH*WW)   // 20480

// ---------------- Kernel 1: prep ----------------
// region 1: transpose src_feas (V,B,C,H,W) -> srcT (V,B,HW,C)   [V*B*HW*8 threads, sub fastest]
// region 2: transpose ref_fea  (B,C,H,W)   -> refT (B,HW,C)     [B*HW*8 threads, sub fastest]
// region 3: nc_mean output                                      [B*HW threads]
// region 4: projection matrices (rot/trans per (v,b))           [1 block]

__device__ void inv4x4(const float* A, float* Ainv) {
    float M[4][8];
    for (int r = 0; r < 4; ++r) {
        for (int c = 0; c < 4; ++c) { M[r][c] = A[r*4+c]; M[r][c+4] = (r == c) ? 1.f : 0.f; }
    }
    for (int col = 0; col < 4; ++col) {
        int piv = col; float best = fabsf(M[col][col]);
        for (int r = col+1; r < 4; ++r) { float v = fabsf(M[r][col]); if (v > best) { best = v; piv = r; } }
        if (piv != col) {
            for (int c = 0; c < 8; ++c) { float tmp = M[col][c]; M[col][c] = M[piv][c]; M[piv][c] = tmp; }
        }
        float d = 1.0f / M[col][col];
        for (int c = 0; c < 8; ++c) M[col][c] *= d;
        for (int r = 0; r < 4; ++r) {
            if (r == col) continue;
            float f = M[r][col];
            for (int c = 0; c < 8; ++c) M[r][c] -= f * M[col][c];
        }
    }
    for (int r = 0; r < 4; ++r)
        for (int c = 0; c < 4; ++c) Ainv[r*4+c] = M[r][c+4];
}

__global__ __launch_bounds__(256) void k_prep(
    const float* __restrict__ src,        // (V,B,C,H,W)
    float* __restrict__ srcT,             // (V,B,HW,C)
    const float* __restrict__ refF,       // (B,C,H,W)
    float* __restrict__ refT,             // (B,HW,C)
    const float* __restrict__ projm,      // (B,V+1,2,4,4)
    float* __restrict__ rotv,             // (V*B, 12)
    const float* __restrict__ ref_nc_sum, // (B,1,H,W)
    const float* __restrict__ src_nc_sums,// (V,B,1,H,W)
    float* __restrict__ nc_out)           // (B,H,W) -> d_out tail
{
    const int NB1 = (VV*BB*HWPIX*8)/256;   // 2560
    const int NB2 = (BB*HWPIX*8)/256;      // 1280
    const int NB3 = (BB*HWPIX)/256;        // 160
    int bid = blockIdx.x;
    int tid = threadIdx.x;
    if (bid < NB1) {
        int t0 = bid*256 + tid;            // sub fastest -> contiguous stores
        int sub = t0 & 7;                  // channel quad
        int rest = t0 >> 3;                // over V*B*HW
        int pix = rest % HWPIX;
        int vb  = rest / HWPIX;
        const float* s = src + (size_t)vb*CC*HWPIX + (size_t)(sub*4)*HWPIX + pix;
        float4 f;
        f.x = s[0];
        f.y = s[(size_t)1*HWPIX];
        f.z = s[(size_t)2*HWPIX];
        f.w = s[(size_t)3*HWPIX];
        float4* dst = (float4*)(srcT + ((size_t)vb*HWPIX + pix)*CC);
        dst[sub] = f;
    } else if (bid < NB1 + NB2) {
        int t0 = (bid - NB1)*256 + tid;
        int sub = t0 & 7;
        int rest = t0 >> 3;                // over B*HW
        int pix = rest % HWPIX;
        int b   = rest / HWPIX;
        const float* s = refF + (size_t)b*CC*HWPIX + (size_t)(sub*4)*HWPIX + pix;
        float4 f;
        f.x = s[0];
        f.y = s[(size_t)1*HWPIX];
        f.z = s[(size_t)2*HWPIX];
        f.w = s[(size_t)3*HWPIX];
        float4* dst = (float4*)(refT + ((size_t)b*HWPIX + pix)*CC);
        dst[sub] = f;
    } else if (bid < NB1 + NB2 + NB3) {
        int gid = (bid - NB1 - NB2)*256 + tid;   // over B*HW
        float s = 0.f;
        float rn = ref_nc_sum[gid];
        #pragma unroll
        for (int v = 0; v < VV; ++v)
            s += (rn + src_nc_sums[(size_t)v*BB*HWPIX + gid]) * 0.5f;
        nc_out[gid] = s / (float)VV;
    } else {
        if (tid < VV*BB) {
            int vb = tid;
            int v = vb / BB;
            int b = vb % BB;
            const float* E = projm + ((size_t)(b*(VV+1) + 0)*2 + 0)*16;
            const float* K = projm + ((size_t)(b*(VV+1) + 0)*2 + 1)*16;
            float refN[16];
            for (int r = 0; r < 3; ++r)
                for (int c = 0; c < 4; ++c)
                    refN[r*4+c] = K[r*4+0]*E[0*4+c] + K[r*4+1]*E[1*4+c] + K[r*4+2]*E[2*4+c];
            for (int c = 0; c < 4; ++c) refN[12+c] = E[12+c];
            const float* Es = projm + ((size_t)(b*(VV+1) + (v+1))*2 + 0)*16;
            const float* Ks = projm + ((size_t)(b*(VV+1) + (v+1))*2 + 1)*16;
            float srcN[16];
            for (int r = 0; r < 3; ++r)
                for (int c = 0; c < 4; ++c)
                    srcN[r*4+c] = Ks[r*4+0]*Es[0*4+c] + Ks[r*4+1]*Es[1*4+c] + Ks[r*4+2]*Es[2*4+c];
            for (int c = 0; c < 4; ++c) srcN[12+c] = Es[12+c];
            float refI[16];
            inv4x4(refN, refI);
            float P[16];
            for (int r = 0; r < 4; ++r)
                for (int c = 0; c < 4; ++c) {
                    float a = 0.f;
                    for (int k = 0; k < 4; ++k) a += srcN[r*4+k]*refI[k*4+c];
                    P[r*4+c] = a;
                }
            float* o = rotv + vb*12;
            o[0]=P[0]; o[1]=P[1]; o[2]=P[2];
            o[3]=P[4]; o[4]=P[5]; o[5]=P[6];
            o[6]=P[8]; o[7]=P[9]; o[8]=P[10];
            o[9]=P[3]; o[10]=P[7]; o[11]=P[11];
        }
    }
}

// ---------------- Kernel 2: warp + channel contraction ----------------
// 4 lanes per (v,b,pixel); lane `sub` owns channels [8*sub, 8*sub+8).
// t written as float4 every 4 depths into (V,B,HW,D) layout.

__global__ __launch_bounds__(256, 4) void k_warp(
    const float* __restrict__ srcT,   // (V,B,HW,C)
    const float* __restrict__ refT,   // (B,HW,C)
    const float* __restrict__ regw,   // (C)
    const float* __restrict__ depthv, // (B,D,H,W)
    const float* __restrict__ rotv,   // (V*B,12)
    float* __restrict__ tout,         // (V,B,HW,D)
    float* __restrict__ entout)       // (V,B,HW)
{
    int gid = blockIdx.x*256 + threadIdx.x;   // over V*B*HW*4
    int sub = gid & 3;
    int gp  = gid >> 2;
    int pix = gp % HWPIX;
    int vb  = gp / HWPIX;
    int b   = vb % BB;
    float fx = (float)(pix % WW);
    float fy = (float)(pix / WW);

    const float* R = rotv + vb*12;
    float rx = fmaf(R[0], fx, fmaf(R[1], fy, R[2]));
    float ry = fmaf(R[3], fx, fmaf(R[4], fy, R[5]));
    float rz = fmaf(R[6], fx, fmaf(R[7], fy, R[8]));
    float tx = R[9], ty = R[10], tz = R[11];

    const float4* rt4 = (const float4*)(refT + ((size_t)b*HWPIX + pix)*CC);
    float4 rf0 = rt4[sub*2], rf1 = rt4[sub*2+1];
    const float4* rw4 = (const float4*)regw;
    float4 q0 = rw4[sub*2], q1 = rw4[sub*2+1];
    float4 gf0 = make_float4(rf0.x*q0.x, rf0.y*q0.y, rf0.z*q0.z, rf0.w*q0.w);
    float4 gf1 = make_float4(rf1.x*q1.x, rf1.y*q1.y, rf1.z*q1.z, rf1.w*q1.w);

    const float4* sb4 = (const float4*)(srcT + (size_t)vb*HWPIX*CC);
    const float* dv = depthv + (size_t)b*DD*HWPIX + pix;
    float4* tp4 = (float4*)(tout + ((size_t)vb*HWPIX + pix)*DD);

    float m = -INFINITY, Zs = 0.f, S1 = 0.f;
    for (int k = 0; k < 12; ++k) {
        float tq[4];
        #pragma unroll
        for (int j = 0; j < 4; ++j) {
            int d = 4*k + j;
            float dep = dv[(size_t)d*HWPIX];
            float X  = fmaf(rx, dep, tx);
            float Y  = fmaf(ry, dep, ty);
            float Zc = fmaf(rz, dep, tz);
            float z  = (fabsf(Zc) < 1e-6f) ? 1e-6f : Zc;
            float iz = 1.0f / z;
            float px = X * iz;
            float py = Y * iz;
            float x0f = floorf(px), y0f = floorf(py);
            float wx = px - x0f, wy = py - y0f;
            int x0 = (int)x0f, y0 = (int)y0f;
            int x1 = x0 + 1, y1 = y0 + 1;
            float v00 = (x0 >= 0 && x0 < WW && y0 >= 0 && y0 < HH) ? 1.f : 0.f;
            float v01 = (x1 >= 0 && x1 < WW && y0 >= 0 && y0 < HH) ? 1.f : 0.f;
            float v10 = (x0 >= 0 && x0 < WW && y1 >= 0 && y1 < HH) ? 1.f : 0.f;
            float v11 = (x1 >= 0 && x1 < WW && y1 >= 0 && y1 < HH) ? 1.f : 0.f;
            float w00 = (1.f-wx)*(1.f-wy)*v00;
            float w01 = wx*(1.f-wy)*v01;
            float w10 = (1.f-wx)*wy*v10;
            float w11 = wx*wy*v11;
            int xc0 = min(max(x0, 0), WW-1), xc1 = min(max(x1, 0), WW-1);
            int yc0 = min(max(y0, 0), HH-1), yc1 = min(max(y1, 0), HH-1);
            int r0 = yc0*(WW*8), r1 = yc1*(WW*8);
            int c0 = (xc0<<3) + (sub<<1), c1 = (xc1<<3) + (sub<<1);
            float4 A0 = sb4[r0 + c0], A1 = sb4[r0 + c0 + 1];
            float4 B0 = sb4[r0 + c1], B1 = sb4[r0 + c1 + 1];
            float4 C0 = sb4[r1 + c0], C1 = sb4[r1 + c0 + 1];
            float4 D0 = sb4[r1 + c1], D1 = sb4[r1 + c1 + 1];
            float m0 = fmaf(w00, A0.x, fmaf(w01, B0.x, fmaf(w10, C0.x, w11*D0.x)));
            float m1 = fmaf(w00, A0.y, fmaf(w01, B0.y, fmaf(w10, C0.y, w11*D0.y)));
            float m2 = fmaf(w00, A0.z, fmaf(w01, B0.z, fmaf(w10, C0.z, w11*D0.z)));
            float m3 = fmaf(w00, A0.w, fmaf(w01, B0.w, fmaf(w10, C0.w, w11*D0.w)));
            float m4 = fmaf(w00, A1.x, fmaf(w01, B1.x, fmaf(w10, C1.x, w11*D1.x)));
            float m5 = fmaf(w00, A1.y, fmaf(w01, B1.y, fmaf(w10, C1.y, w11*D1.y)));
            float m6 = fmaf(w00, A1.z, fmaf(w01, B1.z, fmaf(w10, C1.z, w11*D1.z)));
            float m7 = fmaf(w00, A1.w, fmaf(w01, B1.w, fmaf(w10, C1.w, w11*D1.w)));
            float s = fmaf(m0, rf0.x, fmaf(m1, rf0.y, fmaf(m2, rf0.z, fmaf(m3, rf0.w,
                      fmaf(m4, rf1.x, fmaf(m5, rf1.y, fmaf(m6, rf1.z, m7*rf1.w)))))));
            float t = fmaf(m0, gf0.x, fmaf(m1, gf0.y, fmaf(m2, gf0.z, fmaf(m3, gf0.w,
                      fmaf(m4, gf1.x, fmaf(m5, gf1.y, fmaf(m6, gf1.z, m7*gf1.w)))))));
            s += __shfl_xor(s, 1); s += __shfl_xor(s, 2);
            t += __shfl_xor(t, 1); t += __shfl_xor(t, 2);
            tq[j] = t;
            float mn = fmaxf(m, s);
            float aold = __expf(m - mn);
            float e    = __expf(s - mn);
            Zs = fmaf(Zs, aold, e);
            S1 = fmaf(S1, aold, s*e);
            m = mn;
        }
        if (sub == (k & 3))
            tp4[k] = make_float4(tq[0], tq[1], tq[2], tq[3]);
    }
    if (sub == 0)
        entout[(size_t)vb*HWPIX + pix] = m + __logf(Zs) - S1/Zs;
}

// ---------------- Kernel 3: conv(vis) + combine + softmax + depth/conf ----------------
// 4 lanes per ref pixel: conv channels split 8/lane, depths split 12/lane (contiguous).

__global__ __launch_bounds__(256, 2) void k_final(
    const float* __restrict__ tbuf,   // (V,B,HW,D)
    const float* __restrict__ entbuf, // (V,B,HW)
    const float* __restrict__ ref_nc, // (B,1,H,W)
    const float* __restrict__ w1,     // (32,2,3,3)
    const float* __restrict__ gamma,  // (32)
    const float* __restrict__ beta,   // (32)
    const float* __restrict__ w2,     // (1,32,1,1)
    const float* __restrict__ b2,     // (1)
    const float* __restrict__ regb,   // (1)
    const float* __restrict__ depthv, // (B,D,H,W)
    float* __restrict__ dout)         // depth at 0, conf at B*HW
{
    // weights LDS, stride 24 per channel: ent taps at [0..9), nc taps at [12..21)
    __shared__ float sw[32*24];
    __shared__ float sscale[32], sbeta[32], sw2[32];
    for (int i = threadIdx.x; i < 576; i += 256) {
        int o = i / 18, k = i % 18;
        sw[o*24 + (k < 9 ? k : k + 3)] = w1[i];
    }
    if (threadIdx.x < 32) {
        sscale[threadIdx.x] = gamma[threadIdx.x] / sqrtf(1.0f + 1e-5f);
        sbeta[threadIdx.x]  = beta[threadIdx.x];
        sw2[threadIdx.x]    = w2[threadIdx.x];
    }
    __syncthreads();
    float bias2 = b2[0], rb = regb[0];

    int gid = blockIdx.x*256 + threadIdx.x;  // over B*HW*4
    int sub = gid & 3;
    int gp  = gid >> 2;
    int pix = gp % HWPIX;
    int b   = gp / HWPIX;
    int x = pix % WW, y = pix / WW;

    // gather windows (shared nc window once; entropy per view)
    float wnc[9], went[VV][9];
    {
        const float* nb = ref_nc + (size_t)b*HWPIX;
        #pragma unroll
        for (int ky = 0; ky < 3; ++ky) {
            #pragma unroll
            for (int kx = 0; kx < 3; ++kx) {
                int yy = y + ky - 1, xx = x + kx - 1;
                bool ok = (yy >= 0 && yy < HH && xx >= 0 && xx < WW);
                int q = yy*WW + xx;
                wnc[ky*3+kx] = ok ? nb[q] : 0.f;
                #pragma unroll
                for (int v = 0; v < VV; ++v) {
                    const float* eb = entbuf + (size_t)(v*BB + b)*HWPIX;
                    went[v][ky*3+kx] = ok ? eb[q] : 0.f;
                }
            }
        }
    }

    // nc partial conv (view-independent), 8 channels per lane
    float ncpart[8];
    #pragma unroll
    for (int j = 0; j < 8; ++j) {
        int o = sub*8 + j;
        const float* wb = sw + o*24;
        float4 n0 = *(const float4*)(wb + 12);
        float4 n1 = *(const float4*)(wb + 16);
        float n8 = wb[20];
        float a = n8 * wnc[8];
        a = fmaf(n0.x, wnc[0], a); a = fmaf(n0.y, wnc[1], a);
        a = fmaf(n0.z, wnc[2], a); a = fmaf(n0.w, wnc[3], a);
        a = fmaf(n1.x, wnc[4], a); a = fmaf(n1.y, wnc[5], a);
        a = fmaf(n1.z, wnc[6], a); a = fmaf(n1.w, wnc[7], a);
        ncpart[j] = a;
    }

    float vw[VV]; float vwsum = 0.f;
    #pragma unroll
    for (int v = 0; v < VV; ++v) {
        float accp = 0.f;
        #pragma unroll
        for (int j = 0; j < 8; ++j) {
            int o = sub*8 + j;
            const float* wb = sw + o*24;
            float4 e0 = *(const float4*)(wb);
            float4 e1 = *(const float4*)(wb + 4);
            float e8 = wb[8];
            float a = fmaf(e8, went[v][8], ncpart[j]);
            a = fmaf(e0.x, went[v][0], a); a = fmaf(e0.y, went[v][1], a);
            a = fmaf(e0.z, went[v][2], a); a = fmaf(e0.w, went[v][3], a);
            a = fmaf(e1.x, went[v][4], a); a = fmaf(e1.y, went[v][5], a);
            a = fmaf(e1.z, went[v][6], a); a = fmaf(e1.w, went[v][7], a);
            a = fmaf(a, sscale[o], sbeta[o]);
            a = fmaxf(a, 0.f);
            accp = fmaf(a, sw2[o], accp);
        }
        accp += __shfl_xor(accp, 1); accp += __shfl_xor(accp, 2);
        float vv = 1.f / (1.f + __expf(-(accp + bias2)));
        vw[v] = vv; vwsum += vv;
    }
    float ivw = 1.f / vwsum;

    // depths: lane owns d in [12*sub, 12*sub+12), contiguous float4 reads
    const float4* tp0 = (const float4*)(tbuf + ((size_t)(0*BB + b)*HWPIX + pix)*DD);
    const float4* tp1 = (const float4*)(tbuf + ((size_t)(1*BB + b)*HWPIX + pix)*DD);
    float pre[12];
    float mx = -INFINITY;
    #pragma unroll
    for (int r = 0; r < 3; ++r) {
        float4 a0 = tp0[sub*3 + r];
        float4 a1 = tp1[sub*3 + r];
        float p0 = fmaf(fmaf(vw[0], a0.x, vw[1]*a1.x), ivw, rb);
        float p1 = fmaf(fmaf(vw[0], a0.y, vw[1]*a1.y), ivw, rb);
        float p2 = fmaf(fmaf(vw[0], a0.z, vw[1]*a1.z), ivw, rb);
        float p3 = fmaf(fmaf(vw[0], a0.w, vw[1]*a1.w), ivw, rb);
        pre[r*4+0] = p0; pre[r*4+1] = p1; pre[r*4+2] = p2; pre[r*4+3] = p3;
        mx = fmaxf(mx, fmaxf(fmaxf(p0, p1), fmaxf(p2, p3)));
    }
    mx = fmaxf(mx, __shfl_xor(mx, 1));
    mx = fmaxf(mx, __shfl_xor(mx, 2));

    const float* dvp = depthv + (size_t)b*DD*HWPIX + pix;
    float Zp = 0.f, kp = 0.f, dp = 0.f;
    float ev[12];
    #pragma unroll
    for (int i = 0; i < 12; ++i) {
        int d = sub*12 + i;
        float e = __expf(pre[i] - mx);
        ev[i] = e;
        Zp += e;
        kp = fmaf((float)d, e, kp);
        dp = fmaf(dvp[(size_t)d*HWPIX], e, dp);
    }
    Zp += __shfl_xor(Zp, 1); Zp += __shfl_xor(Zp, 2);
    kp += __shfl_xor(kp, 1); kp += __shfl_xor(kp, 2);
    dp += __shfl_xor(dp, 1); dp += __shfl_xor(dp, 2);

    float iZ = 1.f / Zp;
    float depth = dp * iZ;
    float didx  = kp * iZ;
    float r = rintf(didx);                  // round half-to-even, matches jnp.round
    r = fminf(fmaxf(r, 0.f), (float)(DD-1));
    int idx = (int)r;
    float cfp = 0.f;
    #pragma unroll
    for (int i = 0; i < 12; ++i) {
        int d = sub*12 + i;
        cfp += (d >= idx-1 && d <= idx+2) ? ev[i] : 0.f;
    }
    cfp += __shfl_xor(cfp, 1); cfp += __shfl_xor(cfp, 2);

    if (sub == 0) {
        dout[(size_t)b*HWPIX + pix] = depth;
        dout[(size_t)BB*HWPIX + (size_t)b*HWPIX + pix] = cfp * iZ;
    }
}

extern "C" void kernel_launch(void* const* d_in, const int* in_sizes, int n_in,
                              void* d_out, int out_size, void* d_ws, size_t ws_size,
                              hipStream_t stream) {
    const float* ref_fea     = (const float*)d_in[0];
    const float* src_feas    = (const float*)d_in[1];
    const float* ref_nc      = (const float*)d_in[2];
    const float* ref_nc_sum  = (const float*)d_in[3];
    const float* src_nc_sums = (const float*)d_in[4];
    const float* projm       = (const float*)d_in[5];
    const float* depthv      = (const float*)d_in[6];
    const float* w1          = (const float*)d_in[7];
    const float* gamma       = (const float*)d_in[8];
    const float* beta        = (const float*)d_in[9];
    const float* w2          = (const float*)d_in[10];
    const float* b2v         = (const float*)d_in[11];
    const float* regw        = (const float*)d_in[12];
    const float* regb        = (const float*)d_in[13];
    float* out = (float*)d_out;
    float* ws  = (float*)d_ws;

    float* rotv   = ws;                                   // 48 floats (pad to 64)
    float* srcT   = ws + 64;                              // V*B*HW*C = 2,621,440
    float* refT   = srcT + (size_t)VV*BB*HWPIX*CC;        // B*HW*C = 1,310,720
    float* tbuf   = refT + (size_t)BB*HWPIX*CC;           // V*B*HW*D = 7,864,320
    float* entbuf = tbuf + (size_t)VV*BB*HWPIX*DD;        // V*B*HW = 81,920

    const int NB1 = (VV*BB*HWPIX*8)/256;   // 2560
    const int NB2 = (BB*HWPIX*8)/256;      // 1280
    const int NB3 = (BB*HWPIX)/256;        // 160

    k_prep<<<NB1 + NB2 + NB3 + 1, 256, 0, stream>>>(src_feas, srcT, ref_fea, refT,
                                                    projm, rotv, ref_nc_sum, src_nc_sums,
                                                    out + (size_t)2*BB*HWPIX);
    k_warp<<<(VV*BB*HWPIX*4)/256, 256, 0, stream>>>(srcT, refT, regw, depthv,
                                                    rotv, tbuf, entbuf);
    k_final<<<(BB*HWPIX*4)/256, 256, 0, stream>>>(tbuf, entbuf, ref_nc, w1, gamma,
                                                  beta, w2, b2v, regb, depthv, out);
}

// Round 5
// 121.343 us; speedup vs baseline: 2.2360x; 2.2360x over previous
//
#include <hip/hip_runtime.h>
#include <math.h>

// Problem constants (from reference): B,V,C,D,H,W = 2,2,32,48,128,160
#define BB 2
#define VV 2
#define CC 32
#define DD 48
#define HH 128
#define WW 160
#define HWPIX (HH*WW)   // 20480

// ---------------- Kernel 1: prep ----------------
__device__ void inv4x4(const float* A, float* Ainv) {
    float M[4][8];
    for (int r = 0; r < 4; ++r) {
        for (int c = 0; c < 4; ++c) { M[r][c] = A[r*4+c]; M[r][c+4] = (r == c) ? 1.f : 0.f; }
    }
    for (int col = 0; col < 4; ++col) {
        int piv = col; float best = fabsf(M[col][col]);
        for (int r = col+1; r < 4; ++r) { float v = fabsf(M[r][col]); if (v > best) { best = v; piv = r; } }
        if (piv != col) {
            for (int c = 0; c < 8; ++c) { float tmp = M[col][c]; M[col][c] = M[piv][c]; M[piv][c] = tmp; }
        }
        float d = 1.0f / M[col][col];
        for (int c = 0; c < 8; ++c) M[col][c] *= d;
        for (int r = 0; r < 4; ++r) {
            if (r == col) continue;
            float f = M[r][col];
            for (int c = 0; c < 8; ++c) M[r][c] -= f * M[col][c];
        }
    }
    for (int r = 0; r < 4; ++r)
        for (int c = 0; c < 4; ++c) Ainv[r*4+c] = M[r][c+4];
}

__global__ __launch_bounds__(256) void k_prep(
    const float* __restrict__ src,        // (V,B,C,H,W)
    float* __restrict__ srcT,             // (V,B,HW,C)
    const float* __restrict__ refF,       // (B,C,H,W)
    float* __restrict__ refT,             // (B,HW,C)
    const float* __restrict__ projm,      // (B,V+1,2,4,4)
    float* __restrict__ rotv,             // (V*B, 12)
    const float* __restrict__ ref_nc_sum, // (B,1,H,W)
    const float* __restrict__ src_nc_sums,// (V,B,1,H,W)
    float* __restrict__ nc_out)           // (B,H,W) -> d_out tail
{
    const int NB1 = (VV*BB*HWPIX*8)/256;   // 2560
    const int NB2 = (BB*HWPIX*8)/256;      // 1280
    const int NB3 = (BB*HWPIX)/256;        // 160
    int bid = blockIdx.x;
    int tid = threadIdx.x;
    if (bid < NB1) {
        int t0 = bid*256 + tid;            // sub fastest -> contiguous stores
        int sub = t0 & 7;                  // channel quad
        int rest = t0 >> 3;                // over V*B*HW
        int pix = rest % HWPIX;
        int vb  = rest / HWPIX;
        const float* s = src + (size_t)vb*CC*HWPIX + (size_t)(sub*4)*HWPIX + pix;
        float4 f;
        f.x = s[0];
        f.y = s[(size_t)1*HWPIX];
        f.z = s[(size_t)2*HWPIX];
        f.w = s[(size_t)3*HWPIX];
        float4* dst = (float4*)(srcT + ((size_t)vb*HWPIX + pix)*CC);
        dst[sub] = f;
    } else if (bid < NB1 + NB2) {
        int t0 = (bid - NB1)*256 + tid;
        int sub = t0 & 7;
        int rest = t0 >> 3;                // over B*HW
        int pix = rest % HWPIX;
        int b   = rest / HWPIX;
        const float* s = refF + (size_t)b*CC*HWPIX + (size_t)(sub*4)*HWPIX + pix;
        float4 f;
        f.x = s[0];
        f.y = s[(size_t)1*HWPIX];
        f.z = s[(size_t)2*HWPIX];
        f.w = s[(size_t)3*HWPIX];
        float4* dst = (float4*)(refT + ((size_t)b*HWPIX + pix)*CC);
        dst[sub] = f;
    } else if (bid < NB1 + NB2 + NB3) {
        int gid = (bid - NB1 - NB2)*256 + tid;   // over B*HW
        float s = 0.f;
        float rn = ref_nc_sum[gid];
        #pragma unroll
        for (int v = 0; v < VV; ++v)
            s += (rn + src_nc_sums[(size_t)v*BB*HWPIX + gid]) * 0.5f;
        nc_out[gid] = s / (float)VV;
    } else {
        if (tid < VV*BB) {
            int vb = tid;
            int v = vb / BB;
            int b = vb % BB;
            const float* E = projm + ((size_t)(b*(VV+1) + 0)*2 + 0)*16;
            const float* K = projm + ((size_t)(b*(VV+1) + 0)*2 + 1)*16;
            float refN[16];
            for (int r = 0; r < 3; ++r)
                for (int c = 0; c < 4; ++c)
                    refN[r*4+c] = K[r*4+0]*E[0*4+c] + K[r*4+1]*E[1*4+c] + K[r*4+2]*E[2*4+c];
            for (int c = 0; c < 4; ++c) refN[12+c] = E[12+c];
            const float* Es = projm + ((size_t)(b*(VV+1) + (v+1))*2 + 0)*16;
            const float* Ks = projm + ((size_t)(b*(VV+1) + (v+1))*2 + 1)*16;
            float srcN[16];
            for (int r = 0; r < 3; ++r)
                for (int c = 0; c < 4; ++c)
                    srcN[r*4+c] = Ks[r*4+0]*Es[0*4+c] + Ks[r*4+1]*Es[1*4+c] + Ks[r*4+2]*Es[2*4+c];
            for (int c = 0; c < 4; ++c) srcN[12+c] = Es[12+c];
            float refI[16];
            inv4x4(refN, refI);
            float P[16];
            for (int r = 0; r < 4; ++r)
                for (int c = 0; c < 4; ++c) {
                    float a = 0.f;
                    for (int k = 0; k < 4; ++k) a += srcN[r*4+k]*refI[k*4+c];
                    P[r*4+c] = a;
                }
            float* o = rotv + vb*12;
            o[0]=P[0]; o[1]=P[1]; o[2]=P[2];
            o[3]=P[4]; o[4]=P[5]; o[5]=P[6];
            o[6]=P[8]; o[7]=P[9]; o[8]=P[10];
            o[9]=P[3]; o[10]=P[7]; o[11]=P[11];
        }
    }
}

// ---------------- Kernel 2: warp + channel contraction via G-table ----------------
// 4 lanes per (v,b,pixel). The per-pixel epipolar sweep over D spans <2 px in x
// and <1 px in y (incl. FP-jitter integer straddle), so precompute
// G(q)=<ref,src(q)>, T(q)=<ref*regw,src(q)> on a 4x3 corner grid whose origin is
// the floor of the runtime min of projected coords; each depth then needs 4 LDS
// float2 lookups + 8 FMA.
// Coverage proof: span_x < 2  => x0-xlo in {0,1,2}, x1 <= xlo+3 = NXQ-1  (ok)
//                 span_y < 1  => y0-ylo in {0,1},   y1 <= ylo+2 = NYQ-1  (ok)

#define NXQ 4
#define NYQ 3
#define GSTRIDE 26   // 12 float2 + 2 pad per group

__global__ __launch_bounds__(256, 4) void k_warp(
    const float* __restrict__ srcT,   // (V,B,HW,C)
    const float* __restrict__ refT,   // (B,HW,C)
    const float* __restrict__ regw,   // (C)
    const float* __restrict__ depthv, // (B,D,H,W)
    const float* __restrict__ rotv,   // (V*B,12)
    float* __restrict__ tout,         // (V,B,HW,D)
    float* __restrict__ entout)       // (V,B,HW)
{
    __shared__ float sGT[64 * GSTRIDE];

    int gid = blockIdx.x*256 + threadIdx.x;   // over V*B*HW*4
    int sub = gid & 3;
    int gp  = gid >> 2;
    int pix = gp % HWPIX;
    int vb  = gp / HWPIX;
    int b   = vb % BB;
    int grp = threadIdx.x >> 2;               // group within block
    float* gt = sGT + grp * GSTRIDE;

    float fx = (float)(pix % WW);
    float fy = (float)(pix / WW);

    const float* R = rotv + vb*12;
    float rx = fmaf(R[0], fx, fmaf(R[1], fy, R[2]));
    float ry = fmaf(R[3], fx, fmaf(R[4], fy, R[5]));
    float rz = fmaf(R[6], fx, fmaf(R[7], fy, R[8]));
    float tx = R[9], ty = R[10], tz = R[11];

    // lane's 8 ref channels
    const float4* rt4 = (const float4*)(refT + ((size_t)b*HWPIX + pix)*CC);
    float4 rf0 = rt4[sub*2], rf1 = rt4[sub*2+1];
    const float4* rw4 = (const float4*)regw;
    float4 q0 = rw4[sub*2], q1 = rw4[sub*2+1];
    float4 gf0 = make_float4(rf0.x*q0.x, rf0.y*q0.y, rf0.z*q0.z, rf0.w*q0.w);
    float4 gf1 = make_float4(rf1.x*q1.x, rf1.y*q1.y, rf1.z*q1.z, rf1.w*q1.w);

    // ---- Phase B-1: project this lane's 12 depths, keep px,py; track range ----
    const float* dvl = depthv + (size_t)b*DD*HWPIX + (size_t)(sub*12)*HWPIX + pix;
    float pxs[12], pys[12];
    float minx =  1e30f, maxx = -1e30f, miny =  1e30f, maxy = -1e30f;
    #pragma unroll
    for (int i = 0; i < 12; ++i) {
        float dep = dvl[(size_t)i*HWPIX];
        float X  = fmaf(rx, dep, tx);
        float Y  = fmaf(ry, dep, ty);
        float Zc = fmaf(rz, dep, tz);
        float z  = (fabsf(Zc) < 1e-6f) ? 1e-6f : Zc;
        float iz = 1.0f / z;
        float pxd = X * iz, pyd = Y * iz;
        pxs[i] = pxd; pys[i] = pyd;
        minx = fminf(minx, pxd); maxx = fmaxf(maxx, pxd);
        miny = fminf(miny, pyd); maxy = fmaxf(maxy, pyd);
    }
    // combine range over the 4 lanes of the group
    #pragma unroll
    for (int msk = 1; msk < 4; msk <<= 1) {
        minx = fminf(minx, __shfl_xor(minx, msk));
        miny = fminf(miny, __shfl_xor(miny, msk));
    }
    // candidate grid origin (floor of min); clamp to sane ints
    float xlof = floorf(fminf(fmaxf(minx, -1e8f), 1e8f));
    float ylof = floorf(fminf(fmaxf(miny, -1e8f), 1e8f));
    int xlo = (int)xlof;
    int ylo = (int)ylof;

    // ---- Phase A: build G/T table for NXQ x NYQ candidate corners ----
    const float4* sb4 = (const float4*)(srcT + (size_t)vb*HWPIX*CC);
    #pragma unroll
    for (int qi = 0; qi < NXQ*NYQ; ++qi) {
        int dx = qi & (NXQ-1), dy = qi >> 2;
        int xi = min(max(xlo + dx, 0), WW-1);
        int yi = min(max(ylo + dy, 0), HH-1);
        int base = (yi*WW + xi)*(CC/4) + sub*2;
        float4 s0 = sb4[base], s1 = sb4[base + 1];
        float G = fmaf(s0.x, rf0.x, fmaf(s0.y, rf0.y, fmaf(s0.z, rf0.z, fmaf(s0.w, rf0.w,
                  fmaf(s1.x, rf1.x, fmaf(s1.y, rf1.y, fmaf(s1.z, rf1.z, s1.w*rf1.w)))))));
        float T = fmaf(s0.x, gf0.x, fmaf(s0.y, gf0.y, fmaf(s0.z, gf0.z, fmaf(s0.w, gf0.w,
                  fmaf(s1.x, gf1.x, fmaf(s1.y, gf1.y, fmaf(s1.z, gf1.z, s1.w*gf1.w)))))));
        G += __shfl_xor(G, 1); G += __shfl_xor(G, 2);
        T += __shfl_xor(T, 1); T += __shfl_xor(T, 2);
        if (sub == (qi & 3)) {
            *(float2*)(gt + qi*2) = make_float2(G, T);
        }
    }
    // same-wave LDS dependency; compiler inserts lgkmcnt waits.

    // ---- Phase B-2: depth sweep with table lookups ----
    float t12[12];
    float m = -INFINITY, Zs = 0.f, S1 = 0.f;
    #pragma unroll
    for (int i = 0; i < 12; ++i) {
        float pxd = pxs[i], pyd = pys[i];
        float x0f = floorf(pxd), y0f = floorf(pyd);
        float wx = pxd - x0f, wy = pyd - y0f;
        int x0 = (int)x0f, y0 = (int)y0f;
        int x1 = x0 + 1, y1 = y0 + 1;
        float v00 = (x0 >= 0 && x0 < WW && y0 >= 0 && y0 < HH) ? 1.f : 0.f;
        float v01 = (x1 >= 0 && x1 < WW && y0 >= 0 && y0 < HH) ? 1.f : 0.f;
        float v10 = (x0 >= 0 && x0 < WW && y1 >= 0 && y1 < HH) ? 1.f : 0.f;
        float v11 = (x1 >= 0 && x1 < WW && y1 >= 0 && y1 < HH) ? 1.f : 0.f;
        float w00 = (1.f-wx)*(1.f-wy)*v00;
        float w01 = wx*(1.f-wy)*v01;
        float w10 = (1.f-wx)*wy*v10;
        float w11 = wx*wy*v11;
        int dx0 = min(max(x0 - xlo, 0), NXQ-2);
        int dy0 = min(max(y0 - ylo, 0), NYQ-2);
        int q00 = dy0*NXQ + dx0;
        float2 g00 = *(const float2*)(gt + q00*2);
        float2 g01 = *(const float2*)(gt + q00*2 + 2);
        float2 g10 = *(const float2*)(gt + (q00+NXQ)*2);
        float2 g11 = *(const float2*)(gt + (q00+NXQ)*2 + 2);
        float s = fmaf(w00, g00.x, fmaf(w01, g01.x, fmaf(w10, g10.x, w11*g11.x)));
        float t = fmaf(w00, g00.y, fmaf(w01, g01.y, fmaf(w10, g10.y, w11*g11.y)));
        t12[i] = t;
        float mn = fmaxf(m, s);
        float aold = __expf(m - mn);
        float e    = __expf(s - mn);
        Zs = fmaf(Zs, aold, e);
        S1 = fmaf(S1, aold, s*e);
        m = mn;
    }

    // coalesced t store: lane covers d in [12*sub, 12*sub+12), contiguous
    float4* tp4 = (float4*)(tout + ((size_t)vb*HWPIX + pix)*DD + sub*12);
    tp4[0] = make_float4(t12[0], t12[1], t12[2],  t12[3]);
    tp4[1] = make_float4(t12[4], t12[5], t12[6],  t12[7]);
    tp4[2] = make_float4(t12[8], t12[9], t12[10], t12[11]);

    // merge softmax stats across the 4 lanes (each covered 12 depths)
    #pragma unroll
    for (int msk = 1; msk < 4; msk <<= 1) {
        float mo = __shfl_xor(m, msk);
        float Zo = __shfl_xor(Zs, msk);
        float So = __shfl_xor(S1, msk);
        float mn = fmaxf(m, mo);
        float ea = __expf(m - mn);
        float eb = __expf(mo - mn);
        Zs = fmaf(Zs, ea, Zo*eb);
        S1 = fmaf(S1, ea, So*eb);
        m = mn;
    }
    if (sub == 0)
        entout[(size_t)vb*HWPIX + pix] = m + __logf(Zs) - S1/Zs;
}

// ---------------- Kernel 3: conv(vis) + combine + softmax + depth/conf ----------------
__global__ __launch_bounds__(256, 2) void k_final(
    const float* __restrict__ tbuf,   // (V,B,HW,D)
    const float* __restrict__ entbuf, // (V,B,HW)
    const float* __restrict__ ref_nc, // (B,1,H,W)
    const float* __restrict__ w1,     // (32,2,3,3)
    const float* __restrict__ gamma,  // (32)
    const float* __restrict__ beta,   // (32)
    const float* __restrict__ w2,     // (1,32,1,1)
    const float* __restrict__ b2,     // (1)
    const float* __restrict__ regb,   // (1)
    const float* __restrict__ depthv, // (B,D,H,W)
    float* __restrict__ dout)         // depth at 0, conf at B*HW
{
    __shared__ float sw[32*24];
    __shared__ float sscale[32], sbeta[32], sw2[32];
    for (int i = threadIdx.x; i < 576; i += 256) {
        int o = i / 18, k = i % 18;
        sw[o*24 + (k < 9 ? k : k + 3)] = w1[i];
    }
    if (threadIdx.x < 32) {
        sscale[threadIdx.x] = gamma[threadIdx.x] / sqrtf(1.0f + 1e-5f);
        sbeta[threadIdx.x]  = beta[threadIdx.x];
        sw2[threadIdx.x]    = w2[threadIdx.x];
    }
    __syncthreads();
    float bias2 = b2[0], rb = regb[0];

    int gid = blockIdx.x*256 + threadIdx.x;  // over B*HW*4
    int sub = gid & 3;
    int gp  = gid >> 2;
    int pix = gp % HWPIX;
    int b   = gp / HWPIX;
    int x = pix % WW, y = pix / WW;

    float wnc[9], went[VV][9];
    {
        const float* nb = ref_nc + (size_t)b*HWPIX;
        #pragma unroll
        for (int ky = 0; ky < 3; ++ky) {
            #pragma unroll
            for (int kx = 0; kx < 3; ++kx) {
                int yy = y + ky - 1, xx = x + kx - 1;
                bool ok = (yy >= 0 && yy < HH && xx >= 0 && xx < WW);
                int q = yy*WW + xx;
                wnc[ky*3+kx] = ok ? nb[q] : 0.f;
                #pragma unroll
                for (int v = 0; v < VV; ++v) {
                    const float* eb = entbuf + (size_t)(v*BB + b)*HWPIX;
                    went[v][ky*3+kx] = ok ? eb[q] : 0.f;
                }
            }
        }
    }

    float ncpart[8];
    #pragma unroll
    for (int j = 0; j < 8; ++j) {
        int o = sub*8 + j;
        const float* wb = sw + o*24;
        float4 n0 = *(const float4*)(wb + 12);
        float4 n1 = *(const float4*)(wb + 16);
        float n8 = wb[20];
        float a = n8 * wnc[8];
        a = fmaf(n0.x, wnc[0], a); a = fmaf(n0.y, wnc[1], a);
        a = fmaf(n0.z, wnc[2], a); a = fmaf(n0.w, wnc[3], a);
        a = fmaf(n1.x, wnc[4], a); a = fmaf(n1.y, wnc[5], a);
        a = fmaf(n1.z, wnc[6], a); a = fmaf(n1.w, wnc[7], a);
        ncpart[j] = a;
    }

    float vw[VV]; float vwsum = 0.f;
    #pragma unroll
    for (int v = 0; v < VV; ++v) {
        float accp = 0.f;
        #pragma unroll
        for (int j = 0; j < 8; ++j) {
            int o = sub*8 + j;
            const float* wb = sw + o*24;
            float4 e0 = *(const float4*)(wb);
            float4 e1 = *(const float4*)(wb + 4);
            float e8 = wb[8];
            float a = fmaf(e8, went[v][8], ncpart[j]);
            a = fmaf(e0.x, went[v][0], a); a = fmaf(e0.y, went[v][1], a);
            a = fmaf(e0.z, went[v][2], a); a = fmaf(e0.w, went[v][3], a);
            a = fmaf(e1.x, went[v][4], a); a = fmaf(e1.y, went[v][5], a);
            a = fmaf(e1.z, went[v][6], a); a = fmaf(e1.w, went[v][7], a);
            a = fmaf(a, sscale[o], sbeta[o]);
            a = fmaxf(a, 0.f);
            accp = fmaf(a, sw2[o], accp);
        }
        accp += __shfl_xor(accp, 1); accp += __shfl_xor(accp, 2);
        float vv = 1.f / (1.f + __expf(-(accp + bias2)));
        vw[v] = vv; vwsum += vv;
    }
    float ivw = 1.f / vwsum;

    const float4* tp0 = (const float4*)(tbuf + ((size_t)(0*BB + b)*HWPIX + pix)*DD);
    const float4* tp1 = (const float4*)(tbuf + ((size_t)(1*BB + b)*HWPIX + pix)*DD);
    float pre[12];
    float mx = -INFINITY;
    #pragma unroll
    for (int r = 0; r < 3; ++r) {
        float4 a0 = tp0[sub*3 + r];
        float4 a1 = tp1[sub*3 + r];
        float p0 = fmaf(fmaf(vw[0], a0.x, vw[1]*a1.x), ivw, rb);
        float p1 = fmaf(fmaf(vw[0], a0.y, vw[1]*a1.y), ivw, rb);
        float p2 = fmaf(fmaf(vw[0], a0.z, vw[1]*a1.z), ivw, rb);
        float p3 = fmaf(fmaf(vw[0], a0.w, vw[1]*a1.w), ivw, rb);
        pre[r*4+0] = p0; pre[r*4+1] = p1; pre[r*4+2] = p2; pre[r*4+3] = p3;
        mx = fmaxf(mx, fmaxf(fmaxf(p0, p1), fmaxf(p2, p3)));
    }
    mx = fmaxf(mx, __shfl_xor(mx, 1));
    mx = fmaxf(mx, __shfl_xor(mx, 2));

    const float* dvp = depthv + (size_t)b*DD*HWPIX + pix;
    float Zp = 0.f, kp = 0.f, dp = 0.f;
    float ev[12];
    #pragma unroll
    for (int i = 0; i < 12; ++i) {
        int d = sub*12 + i;
        float e = __expf(pre[i] - mx);
        ev[i] = e;
        Zp += e;
        kp = fmaf((float)d, e, kp);
        dp = fmaf(dvp[(size_t)d*HWPIX], e, dp);
    }
    Zp += __shfl_xor(Zp, 1); Zp += __shfl_xor(Zp, 2);
    kp += __shfl_xor(kp, 1); kp += __shfl_xor(kp, 2);
    dp += __shfl_xor(dp, 1); dp += __shfl_xor(dp, 2);

    float iZ = 1.f / Zp;
    float depth = dp * iZ;
    float didx  = kp * iZ;
    float r = rintf(didx);                  // round half-to-even, matches jnp.round
    r = fminf(fmaxf(r, 0.f), (float)(DD-1));
    int idx = (int)r;
    float cfp = 0.f;
    #pragma unroll
    for (int i = 0; i < 12; ++i) {
        int d = sub*12 + i;
        cfp += (d >= idx-1 && d <= idx+2) ? ev[i] : 0.f;
    }
    cfp += __shfl_xor(cfp, 1); cfp += __shfl_xor(cfp, 2);

    if (sub == 0) {
        dout[(size_t)b*HWPIX + pix] = depth;
        dout[(size_t)BB*HWPIX + (size_t)b*HWPIX + pix] = cfp * iZ;
    }
}

extern "C" void kernel_launch(void* const* d_in, const int* in_sizes, int n_in,
                              void* d_out, int out_size, void* d_ws, size_t ws_size,
                              hipStream_t stream) {
    const float* ref_fea     = (const float*)d_in[0];
    const float* src_feas    = (const float*)d_in[1];
    const float* ref_nc      = (const float*)d_in[2];
    const float* ref_nc_sum  = (const float*)d_in[3];
    const float* src_nc_sums = (const float*)d_in[4];
    const float* projm       = (const float*)d_in[5];
    const float* depthv      = (const float*)d_in[6];
    const float* w1          = (const float*)d_in[7];
    const float* gamma       = (const float*)d_in[8];
    const float* beta        = (const float*)d_in[9];
    const float* w2          = (const float*)d_in[10];
    const float* b2v         = (const float*)d_in[11];
    const float* regw        = (const float*)d_in[12];
    const float* regb        = (const float*)d_in[13];
    float* out = (float*)d_out;
    float* ws  = (float*)d_ws;

    float* rotv   = ws;                                   // 48 floats (pad to 64)
    float* srcT   = ws + 64;                              // V*B*HW*C = 2,621,440
    float* refT   = srcT + (size_t)VV*BB*HWPIX*CC;        // B*HW*C = 1,310,720
    float* tbuf   = refT + (size_t)BB*HWPIX*CC;           // V*B*HW*D = 7,864,320
    float* entbuf = tbuf + (size_t)VV*BB*HWPIX*DD;        // V*B*HW = 81,920

    const int NB1 = (VV*BB*HWPIX*8)/256;   // 2560
    const int NB2 = (BB*HWPIX*8)/256;      // 1280
    const int NB3 = (BB*HWPIX)/256;        // 160

    k_prep<<<NB1 + NB2 + NB3 + 1, 256, 0, stream>>>(src_feas, srcT, ref_fea, refT,
                                                    projm, rotv, ref_nc_sum, src_nc_sums,
                                                    out + (size_t)2*BB*HWPIX);
    k_warp<<<(VV*BB*HWPIX*4)/256, 256, 0, stream>>>(srcT, refT, regw, depthv,
                                                    rotv, tbuf, entbuf);
    k_final<<<(BB*HWPIX*4)/256, 256, 0, stream>>>(tbuf, entbuf, ref_nc, w1, gamma,
                                                  beta, w2, b2v, regb, depthv, out);
}

// Round 6
// 117.019 us; speedup vs baseline: 2.3186x; 1.0370x over previous
//
#include <hip/hip_runtime.h>
#include <math.h>

// Problem constants (from reference): B,V,C,D,H,W = 2,2,32,48,128,160
#define BB 2
#define VV 2
#define CC 32
#define DD 48
#define HH 128
#define WW 160
#define HWPIX (HH*WW)   // 20480

// ---------------- Kernel 1: prep ----------------
// region 1: LDS-tiled transpose src (V,B,C,H,W) -> srcT (V,B,HW,C)  [1280 blocks]
// region 2: LDS-tiled transpose ref (B,C,H,W)   -> refT (B,HW,C)    [640 blocks]
// region 3: nc_mean output                                          [160 blocks]
// region 4: projection matrices                                     [1 block]

__device__ void inv4x4(const float* A, float* Ainv) {
    float M[4][8];
    for (int r = 0; r < 4; ++r) {
        for (int c = 0; c < 4; ++c) { M[r][c] = A[r*4+c]; M[r][c+4] = (r == c) ? 1.f : 0.f; }
    }
    for (int col = 0; col < 4; ++col) {
        int piv = col; float best = fabsf(M[col][col]);
        for (int r = col+1; r < 4; ++r) { float v = fabsf(M[r][col]); if (v > best) { best = v; piv = r; } }
        if (piv != col) {
            for (int c = 0; c < 8; ++c) { float tmp = M[col][c]; M[col][c] = M[piv][c]; M[piv][c] = tmp; }
        }
        float d = 1.0f / M[col][col];
        for (int c = 0; c < 8; ++c) M[col][c] *= d;
        for (int r = 0; r < 4; ++r) {
            if (r == col) continue;
            float f = M[r][col];
            for (int c = 0; c < 8; ++c) M[r][c] -= f * M[col][c];
        }
    }
    for (int r = 0; r < 4; ++r)
        for (int c = 0; c < 4; ++c) Ainv[r*4+c] = M[r][c+4];
}

#define TPAD 33   // [64 px][33] : write bank=lane+ch, read bank=px+4q+j -> conflict-free

__global__ __launch_bounds__(256) void k_prep(
    const float* __restrict__ src,        // (V,B,C,H,W)
    float* __restrict__ srcT,             // (V,B,HW,C)
    const float* __restrict__ refF,       // (B,C,H,W)
    float* __restrict__ refT,             // (B,HW,C)
    const float* __restrict__ projm,      // (B,V+1,2,4,4)
    float* __restrict__ rotv,             // (V*B, 12)
    const float* __restrict__ ref_nc_sum, // (B,1,H,W)
    const float* __restrict__ src_nc_sums,// (V,B,1,H,W)
    float* __restrict__ nc_out)           // (B,H,W) -> d_out tail
{
    __shared__ float lt[64*TPAD];
    const int NB1 = VV*BB*HWPIX/64;   // 1280
    const int NB2 = BB*HWPIX/64;      // 640
    const int NB3 = (BB*HWPIX)/256;   // 160
    int bid = blockIdx.x;
    int tid = threadIdx.x;
    if (bid < NB1) {
        int vb  = bid / (HWPIX/64);
        int px0 = (bid % (HWPIX/64)) * 64;
        int lane = tid & 63, wv = tid >> 6;
        const float* sbase = src + (size_t)vb*CC*HWPIX + px0;
        #pragma unroll
        for (int i = 0; i < 8; ++i) {
            int ch = i*4 + wv;
            lt[lane*TPAD + ch] = sbase[(size_t)ch*HWPIX + lane];
        }
        __syncthreads();
        float4* dbase = (float4*)(srcT + ((size_t)vb*HWPIX + px0)*CC);
        #pragma unroll
        for (int k = 0; k < 2; ++k) {
            int idx = k*256 + tid;          // 0..511 = 64 px * 8 q
            int pxl = idx >> 3, q = idx & 7;
            const float* p = lt + pxl*TPAD + q*4;
            dbase[idx] = make_float4(p[0], p[1], p[2], p[3]);
        }
    } else if (bid < NB1 + NB2) {
        int b2  = bid - NB1;
        int b   = b2 / (HWPIX/64);
        int px0 = (b2 % (HWPIX/64)) * 64;
        int lane = tid & 63, wv = tid >> 6;
        const float* sbase = refF + (size_t)b*CC*HWPIX + px0;
        #pragma unroll
        for (int i = 0; i < 8; ++i) {
            int ch = i*4 + wv;
            lt[lane*TPAD + ch] = sbase[(size_t)ch*HWPIX + lane];
        }
        __syncthreads();
        float4* dbase = (float4*)(refT + ((size_t)b*HWPIX + px0)*CC);
        #pragma unroll
        for (int k = 0; k < 2; ++k) {
            int idx = k*256 + tid;
            int pxl = idx >> 3, q = idx & 7;
            const float* p = lt + pxl*TPAD + q*4;
            dbase[idx] = make_float4(p[0], p[1], p[2], p[3]);
        }
    } else if (bid < NB1 + NB2 + NB3) {
        int gid = (bid - NB1 - NB2)*256 + tid;   // over B*HW
        float s = 0.f;
        float rn = ref_nc_sum[gid];
        #pragma unroll
        for (int v = 0; v < VV; ++v)
            s += (rn + src_nc_sums[(size_t)v*BB*HWPIX + gid]) * 0.5f;
        nc_out[gid] = s / (float)VV;
    } else {
        if (tid < VV*BB) {
            int vb = tid;
            int v = vb / BB;
            int b = vb % BB;
            const float* E = projm + ((size_t)(b*(VV+1) + 0)*2 + 0)*16;
            const float* K = projm + ((size_t)(b*(VV+1) + 0)*2 + 1)*16;
            float refN[16];
            for (int r = 0; r < 3; ++r)
                for (int c = 0; c < 4; ++c)
                    refN[r*4+c] = K[r*4+0]*E[0*4+c] + K[r*4+1]*E[1*4+c] + K[r*4+2]*E[2*4+c];
            for (int c = 0; c < 4; ++c) refN[12+c] = E[12+c];
            const float* Es = projm + ((size_t)(b*(VV+1) + (v+1))*2 + 0)*16;
            const float* Ks = projm + ((size_t)(b*(VV+1) + (v+1))*2 + 1)*16;
            float srcN[16];
            for (int r = 0; r < 3; ++r)
                for (int c = 0; c < 4; ++c)
                    srcN[r*4+c] = Ks[r*4+0]*Es[0*4+c] + Ks[r*4+1]*Es[1*4+c] + Ks[r*4+2]*Es[2*4+c];
            for (int c = 0; c < 4; ++c) srcN[12+c] = Es[12+c];
            float refI[16];
            inv4x4(refN, refI);
            float P[16];
            for (int r = 0; r < 4; ++r)
                for (int c = 0; c < 4; ++c) {
                    float a = 0.f;
                    for (int k = 0; k < 4; ++k) a += srcN[r*4+k]*refI[k*4+c];
                    P[r*4+c] = a;
                }
            float* o = rotv + vb*12;
            o[0]=P[0]; o[1]=P[1]; o[2]=P[2];
            o[3]=P[4]; o[4]=P[5]; o[5]=P[6];
            o[6]=P[8]; o[7]=P[9]; o[8]=P[10];
            o[9]=P[3]; o[10]=P[7]; o[11]=P[11];
        }
    }
}

// ---------------- Kernel 2: warp + channel contraction via G-table ----------------
// 4 lanes per (v,b,pixel); 4x3 candidate grid; depth values staged once per block
// in LDS (depth_values is spatially broadcast -> bit-identical).

#define NXQ 4
#define NYQ 3
#define GSTRIDE 26   // 12 float2 + 2 pad per group

__global__ __launch_bounds__(256, 4) void k_warp(
    const float* __restrict__ srcT,   // (V,B,HW,C)
    const float* __restrict__ refT,   // (B,HW,C)
    const float* __restrict__ regw,   // (C)
    const float* __restrict__ depthv, // (B,D,H,W)
    const float* __restrict__ rotv,   // (V*B,12)
    float* __restrict__ tout,         // (V,B,HW,D)
    float* __restrict__ entout)       // (V,B,HW)
{
    __shared__ float sGT[64 * GSTRIDE];
    __shared__ float sdep[DD];

    int gid = blockIdx.x*256 + threadIdx.x;   // over V*B*HW*4
    int sub = gid & 3;
    int gp  = gid >> 2;
    int pix = gp % HWPIX;
    int vb  = gp / HWPIX;                      // uniform per block (64 px/block)
    int b   = vb % BB;
    int grp = threadIdx.x >> 2;
    float* gt = sGT + grp * GSTRIDE;

    if (threadIdx.x < DD)
        sdep[threadIdx.x] = depthv[(size_t)b*DD*HWPIX + (size_t)threadIdx.x*HWPIX];
    __syncthreads();

    float fx = (float)(pix % WW);
    float fy = (float)(pix / WW);

    const float* R = rotv + vb*12;
    float rx = fmaf(R[0], fx, fmaf(R[1], fy, R[2]));
    float ry = fmaf(R[3], fx, fmaf(R[4], fy, R[5]));
    float rz = fmaf(R[6], fx, fmaf(R[7], fy, R[8]));
    float tx = R[9], ty = R[10], tz = R[11];

    // lane's 8 ref channels
    const float4* rt4 = (const float4*)(refT + ((size_t)b*HWPIX + pix)*CC);
    float4 rf0 = rt4[sub*2], rf1 = rt4[sub*2+1];
    const float4* rw4 = (const float4*)regw;
    float4 q0 = rw4[sub*2], q1 = rw4[sub*2+1];
    float4 gf0 = make_float4(rf0.x*q0.x, rf0.y*q0.y, rf0.z*q0.z, rf0.w*q0.w);
    float4 gf1 = make_float4(rf1.x*q1.x, rf1.y*q1.y, rf1.z*q1.z, rf1.w*q1.w);

    // ---- Phase B-1: project this lane's 12 depths; track range ----
    float pxs[12], pys[12];
    float minx =  1e30f, miny =  1e30f;
    #pragma unroll
    for (int i = 0; i < 12; ++i) {
        float dep = sdep[sub*12 + i];
        float X  = fmaf(rx, dep, tx);
        float Y  = fmaf(ry, dep, ty);
        float Zc = fmaf(rz, dep, tz);
        float z  = (fabsf(Zc) < 1e-6f) ? 1e-6f : Zc;
        float iz = 1.0f / z;
        float pxd = X * iz, pyd = Y * iz;
        pxs[i] = pxd; pys[i] = pyd;
        minx = fminf(minx, pxd);
        miny = fminf(miny, pyd);
    }
    #pragma unroll
    for (int msk = 1; msk < 4; msk <<= 1) {
        minx = fminf(minx, __shfl_xor(minx, msk));
        miny = fminf(miny, __shfl_xor(miny, msk));
    }
    float xlof = floorf(fminf(fmaxf(minx, -1e8f), 1e8f));
    float ylof = floorf(fminf(fmaxf(miny, -1e8f), 1e8f));
    int xlo = (int)xlof;
    int ylo = (int)ylof;

    // ---- Phase A: build G/T table for NXQ x NYQ candidate corners ----
    const float4* sb4 = (const float4*)(srcT + (size_t)vb*HWPIX*CC);
    #pragma unroll
    for (int qi = 0; qi < NXQ*NYQ; ++qi) {
        int dx = qi & (NXQ-1), dy = qi >> 2;
        int xi = min(max(xlo + dx, 0), WW-1);
        int yi = min(max(ylo + dy, 0), HH-1);
        int base = (yi*WW + xi)*(CC/4) + sub*2;
        float4 s0 = sb4[base], s1 = sb4[base + 1];
        float G = fmaf(s0.x, rf0.x, fmaf(s0.y, rf0.y, fmaf(s0.z, rf0.z, fmaf(s0.w, rf0.w,
                  fmaf(s1.x, rf1.x, fmaf(s1.y, rf1.y, fmaf(s1.z, rf1.z, s1.w*rf1.w)))))));
        float T = fmaf(s0.x, gf0.x, fmaf(s0.y, gf0.y, fmaf(s0.z, gf0.z, fmaf(s0.w, gf0.w,
                  fmaf(s1.x, gf1.x, fmaf(s1.y, gf1.y, fmaf(s1.z, gf1.z, s1.w*gf1.w)))))));
        G += __shfl_xor(G, 1); G += __shfl_xor(G, 2);
        T += __shfl_xor(T, 1); T += __shfl_xor(T, 2);
        if (sub == (qi & 3)) {
            *(float2*)(gt + qi*2) = make_float2(G, T);
        }
    }

    // ---- Phase B-2: depth sweep with table lookups ----
    float t12[12];
    float m = -INFINITY, Zs = 0.f, S1 = 0.f;
    #pragma unroll
    for (int i = 0; i < 12; ++i) {
        float pxd = pxs[i], pyd = pys[i];
        float x0f = floorf(pxd), y0f = floorf(pyd);
        float wx = pxd - x0f, wy = pyd - y0f;
        int x0 = (int)x0f, y0 = (int)y0f;
        int x1 = x0 + 1, y1 = y0 + 1;
        float v00 = (x0 >= 0 && x0 < WW && y0 >= 0 && y0 < HH) ? 1.f : 0.f;
        float v01 = (x1 >= 0 && x1 < WW && y0 >= 0 && y0 < HH) ? 1.f : 0.f;
        float v10 = (x0 >= 0 && x0 < WW && y1 >= 0 && y1 < HH) ? 1.f : 0.f;
        float v11 = (x1 >= 0 && x1 < WW && y1 >= 0 && y1 < HH) ? 1.f : 0.f;
        float w00 = (1.f-wx)*(1.f-wy)*v00;
        float w01 = wx*(1.f-wy)*v01;
        float w10 = (1.f-wx)*wy*v10;
        float w11 = wx*wy*v11;
        int dx0 = min(max(x0 - xlo, 0), NXQ-2);
        int dy0 = min(max(y0 - ylo, 0), NYQ-2);
        int q00 = dy0*NXQ + dx0;
        float2 g00 = *(const float2*)(gt + q00*2);
        float2 g01 = *(const float2*)(gt + q00*2 + 2);
        float2 g10 = *(const float2*)(gt + (q00+NXQ)*2);
        float2 g11 = *(const float2*)(gt + (q00+NXQ)*2 + 2);
        float s = fmaf(w00, g00.x, fmaf(w01, g01.x, fmaf(w10, g10.x, w11*g11.x)));
        float t = fmaf(w00, g00.y, fmaf(w01, g01.y, fmaf(w10, g10.y, w11*g11.y)));
        t12[i] = t;
        float mn = fmaxf(m, s);
        float aold = __expf(m - mn);
        float e    = __expf(s - mn);
        Zs = fmaf(Zs, aold, e);
        S1 = fmaf(S1, aold, s*e);
        m = mn;
    }

    // coalesced t store: lane covers d in [12*sub, 12*sub+12), contiguous
    float4* tp4 = (float4*)(tout + ((size_t)vb*HWPIX + pix)*DD + sub*12);
    tp4[0] = make_float4(t12[0], t12[1], t12[2],  t12[3]);
    tp4[1] = make_float4(t12[4], t12[5], t12[6],  t12[7]);
    tp4[2] = make_float4(t12[8], t12[9], t12[10], t12[11]);

    // merge softmax stats across the 4 lanes
    #pragma unroll
    for (int msk = 1; msk < 4; msk <<= 1) {
        float mo = __shfl_xor(m, msk);
        float Zo = __shfl_xor(Zs, msk);
        float So = __shfl_xor(S1, msk);
        float mn = fmaxf(m, mo);
        float ea = __expf(m - mn);
        float eb = __expf(mo - mn);
        Zs = fmaf(Zs, ea, Zo*eb);
        S1 = fmaf(S1, ea, So*eb);
        m = mn;
    }
    if (sub == 0)
        entout[(size_t)vb*HWPIX + pix] = m + __logf(Zs) - S1/Zs;
}

// ---------------- Kernel 3: conv(vis) + combine + softmax + depth/conf ----------------
// 8 lanes per ref pixel: conv channels 4/lane, depths 6/lane (contiguous float2 reads).

__global__ __launch_bounds__(256) void k_final(
    const float* __restrict__ tbuf,   // (V,B,HW,D)
    const float* __restrict__ entbuf, // (V,B,HW)
    const float* __restrict__ ref_nc, // (B,1,H,W)
    const float* __restrict__ w1,     // (32,2,3,3)
    const float* __restrict__ gamma,  // (32)
    const float* __restrict__ beta,   // (32)
    const float* __restrict__ w2,     // (1,32,1,1)
    const float* __restrict__ b2,     // (1)
    const float* __restrict__ regb,   // (1)
    const float* __restrict__ depthv, // (B,D,H,W)
    float* __restrict__ dout)         // depth at 0, conf at B*HW
{
    __shared__ float sw[32*24];
    __shared__ float sscale[32], sbeta[32], sw2[32];
    __shared__ float sdep[DD];

    int gid = blockIdx.x*256 + threadIdx.x;  // over B*HW*8
    int sub = gid & 7;
    int gp  = gid >> 3;
    int pix = gp % HWPIX;
    int b   = gp / HWPIX;                    // uniform per block (32 px/block)

    for (int i = threadIdx.x; i < 576; i += 256) {
        int o = i / 18, k = i % 18;
        sw[o*24 + (k < 9 ? k : k + 3)] = w1[i];
    }
    if (threadIdx.x < 32) {
        sscale[threadIdx.x] = gamma[threadIdx.x] / sqrtf(1.0f + 1e-5f);
        sbeta[threadIdx.x]  = beta[threadIdx.x];
        sw2[threadIdx.x]    = w2[threadIdx.x];
    }
    if (threadIdx.x < DD)
        sdep[threadIdx.x] = depthv[(size_t)b*DD*HWPIX + (size_t)threadIdx.x*HWPIX];
    __syncthreads();
    float bias2 = b2[0], rb = regb[0];

    int x = pix % WW, y = pix / WW;

    float wnc[9], went[VV][9];
    {
        const float* nb = ref_nc + (size_t)b*HWPIX;
        #pragma unroll
        for (int ky = 0; ky < 3; ++ky) {
            #pragma unroll
            for (int kx = 0; kx < 3; ++kx) {
                int yy = y + ky - 1, xx = x + kx - 1;
                bool ok = (yy >= 0 && yy < HH && xx >= 0 && xx < WW);
                int q = yy*WW + xx;
                wnc[ky*3+kx] = ok ? nb[q] : 0.f;
                #pragma unroll
                for (int v = 0; v < VV; ++v) {
                    const float* eb = entbuf + (size_t)(v*BB + b)*HWPIX;
                    went[v][ky*3+kx] = ok ? eb[q] : 0.f;
                }
            }
        }
    }

    // nc partial conv (view-independent), 4 channels per lane
    float ncpart[4];
    #pragma unroll
    for (int j = 0; j < 4; ++j) {
        int o = sub*4 + j;
        const float* wb = sw + o*24;
        float4 n0 = *(const float4*)(wb + 12);
        float4 n1 = *(const float4*)(wb + 16);
        float n8 = wb[20];
        float a = n8 * wnc[8];
        a = fmaf(n0.x, wnc[0], a); a = fmaf(n0.y, wnc[1], a);
        a = fmaf(n0.z, wnc[2], a); a = fmaf(n0.w, wnc[3], a);
        a = fmaf(n1.x, wnc[4], a); a = fmaf(n1.y, wnc[5], a);
        a = fmaf(n1.z, wnc[6], a); a = fmaf(n1.w, wnc[7], a);
        ncpart[j] = a;
    }

    float vw[VV]; float vwsum = 0.f;
    #pragma unroll
    for (int v = 0; v < VV; ++v) {
        float accp = 0.f;
        #pragma unroll
        for (int j = 0; j < 4; ++j) {
            int o = sub*4 + j;
            const float* wb = sw + o*24;
            float4 e0 = *(const float4*)(wb);
            float4 e1 = *(const float4*)(wb + 4);
            float e8 = wb[8];
            float a = fmaf(e8, went[v][8], ncpart[j]);
            a = fmaf(e0.x, went[v][0], a); a = fmaf(e0.y, went[v][1], a);
            a = fmaf(e0.z, went[v][2], a); a = fmaf(e0.w, went[v][3], a);
            a = fmaf(e1.x, went[v][4], a); a = fmaf(e1.y, went[v][5], a);
            a = fmaf(e1.z, went[v][6], a); a = fmaf(e1.w, went[v][7], a);
            a = fmaf(a, sscale[o], sbeta[o]);
            a = fmaxf(a, 0.f);
            accp = fmaf(a, sw2[o], accp);
        }
        accp += __shfl_xor(accp, 1); accp += __shfl_xor(accp, 2); accp += __shfl_xor(accp, 4);
        float vv = 1.f / (1.f + __expf(-(accp + bias2)));
        vw[v] = vv; vwsum += vv;
    }
    float ivw = 1.f / vwsum;

    // depths: lane owns d in [6*sub, 6*sub+6); contiguous float2 reads (8B aligned)
    const float* t0p = tbuf + ((size_t)(0*BB + b)*HWPIX + pix)*DD + sub*6;
    const float* t1p = tbuf + ((size_t)(1*BB + b)*HWPIX + pix)*DD + sub*6;
    float tv0[6], tv1[6];
    *(float2*)(tv0+0) = *(const float2*)(t0p+0);
    *(float2*)(tv0+2) = *(const float2*)(t0p+2);
    *(float2*)(tv0+4) = *(const float2*)(t0p+4);
    *(float2*)(tv1+0) = *(const float2*)(t1p+0);
    *(float2*)(tv1+2) = *(const float2*)(t1p+2);
    *(float2*)(tv1+4) = *(const float2*)(t1p+4);

    float pre[6];
    float mx = -INFINITY;
    #pragma unroll
    for (int i = 0; i < 6; ++i) {
        float p = fmaf(fmaf(vw[0], tv0[i], vw[1]*tv1[i]), ivw, rb);
        pre[i] = p;
        mx = fmaxf(mx, p);
    }
    mx = fmaxf(mx, __shfl_xor(mx, 1));
    mx = fmaxf(mx, __shfl_xor(mx, 2));
    mx = fmaxf(mx, __shfl_xor(mx, 4));

    float Zp = 0.f, kp = 0.f, dp = 0.f;
    float ev[6];
    #pragma unroll
    for (int i = 0; i < 6; ++i) {
        int d = sub*6 + i;
        float e = __expf(pre[i] - mx);
        ev[i] = e;
        Zp += e;
        kp = fmaf((float)d, e, kp);
        dp = fmaf(sdep[d], e, dp);
    }
    Zp += __shfl_xor(Zp, 1); Zp += __shfl_xor(Zp, 2); Zp += __shfl_xor(Zp, 4);
    kp += __shfl_xor(kp, 1); kp += __shfl_xor(kp, 2); kp += __shfl_xor(kp, 4);
    dp += __shfl_xor(dp, 1); dp += __shfl_xor(dp, 2); dp += __shfl_xor(dp, 4);

    float iZ = 1.f / Zp;
    float depth = dp * iZ;
    float didx  = kp * iZ;
    float r = rintf(didx);                  // round half-to-even, matches jnp.round
    r = fminf(fmaxf(r, 0.f), (float)(DD-1));
    int idx = (int)r;
    float cfp = 0.f;
    #pragma unroll
    for (int i = 0; i < 6; ++i) {
        int d = sub*6 + i;
        cfp += (d >= idx-1 && d <= idx+2) ? ev[i] : 0.f;
    }
    cfp += __shfl_xor(cfp, 1); cfp += __shfl_xor(cfp, 2); cfp += __shfl_xor(cfp, 4);

    if (sub == 0) {
        dout[(size_t)b*HWPIX + pix] = depth;
        dout[(size_t)BB*HWPIX + (size_t)b*HWPIX + pix] = cfp * iZ;
    }
}

extern "C" void kernel_launch(void* const* d_in, const int* in_sizes, int n_in,
                              void* d_out, int out_size, void* d_ws, size_t ws_size,
                              hipStream_t stream) {
    const float* ref_fea     = (const float*)d_in[0];
    const float* src_feas    = (const float*)d_in[1];
    const float* ref_nc      = (const float*)d_in[2];
    const float* ref_nc_sum  = (const float*)d_in[3];
    const float* src_nc_sums = (const float*)d_in[4];
    const float* projm       = (const float*)d_in[5];
    const float* depthv      = (const float*)d_in[6];
    const float* w1          = (const float*)d_in[7];
    const float* gamma       = (const float*)d_in[8];
    const float* beta        = (const float*)d_in[9];
    const float* w2          = (const float*)d_in[10];
    const float* b2v         = (const float*)d_in[11];
    const float* regw        = (const float*)d_in[12];
    const float* regb        = (const float*)d_in[13];
    float* out = (float*)d_out;
    float* ws  = (float*)d_ws;

    float* rotv   = ws;                                   // 48 floats (pad to 64)
    float* srcT   = ws + 64;                              // V*B*HW*C = 2,621,440
    float* refT   = srcT + (size_t)VV*BB*HWPIX*CC;        // B*HW*C = 1,310,720
    float* tbuf   = refT + (size_t)BB*HWPIX*CC;           // V*B*HW*D = 7,864,320
    float* entbuf = tbuf + (size_t)VV*BB*HWPIX*DD;        // V*B*HW = 81,920

    const int NB1 = VV*BB*HWPIX/64;   // 1280
    const int NB2 = BB*HWPIX/64;      // 640
    const int NB3 = (BB*HWPIX)/256;   // 160

    k_prep<<<NB1 + NB2 + NB3 + 1, 256, 0, stream>>>(src_feas, srcT, ref_fea, refT,
                                                    projm, rotv, ref_nc_sum, src_nc_sums,
                                                    out + (size_t)2*BB*HWPIX);
    k_warp<<<(VV*BB*HWPIX*4)/256, 256, 0, stream>>>(srcT, refT, regw, depthv,
                                                    rotv, tbuf, entbuf);
    k_final<<<(BB*HWPIX*8)/256, 256, 0, stream>>>(tbuf, entbuf, ref_nc, w1, gamma,
                                                  beta, w2, b2v, regb, depthv, out);
}